// Round 12
// baseline (16109.827 us; speedup 1.0000x reference)
//
#include <hip/hip_runtime.h>
#include <hip/hip_bf16.h>

// FF_27650999451977: 2-layer gated RNN (MGU), SEQ=512, B=64, H=IN=512, FP32 I/O.
// Round-12: XCD-local h-exchange v3.
//  - cluster = wg&7 (round-robin wg->XCD heuristic), rank = wg>>3; NO s_getreg
//  - grouping VERIFIED by a bounded sc0 token handshake; any miss -> uniform
//    LLC fallback (the proven round-9 protocol, 2763us)
//  - host checks hipLaunchCooperativeKernel's return; on error does a plain
//    launch (round-6/11 silent-launch-failure class eliminated)
//  - all spins iteration-bounded + ABORT cascade: worst case visible failure
//  - tokens erased at kernel end (no stale false-pass across graph replays)

#define SEQn 512
#define Bn   64
#define Hn   512
#define RING 8
#define BH   32768      // Bn*Hn dwords
#define TILE 8192       // 16*512 dwords

#define C_BAR0  0       // ctrl dword offsets
#define C_FAIL  16
#define C_ABORT 32
#define C_BPF   64      // + mg*32 + ng  (128 dwords)

#define HSHAKE_IT 65536u
#define SPIN_MAIN (1u << 18)
#define SPIN_INIT (1u << 22)

typedef __bf16 bf16x8 __attribute__((ext_vector_type(8)));
typedef float  f32x4  __attribute__((ext_vector_type(4)));
typedef unsigned u32;
typedef unsigned long long u64;
typedef u32 u32x4v __attribute__((ext_vector_type(4)));

__device__ __forceinline__ u32 cload(const u32* p) {
    return __hip_atomic_load(p, __ATOMIC_RELAXED, __HIP_MEMORY_SCOPE_AGENT);
}
__device__ __forceinline__ void cstore(u32* p, u32 v) {
    __hip_atomic_store(p, v, __ATOMIC_RELAXED, __HIP_MEMORY_SCOPE_AGENT);
}
// XCD-L2-scope (sc0-only) single-dword ops
__device__ __forceinline__ u32 l2ld(const u32* p) {
    u32 v;
    asm volatile("global_load_dword %0, %1, off sc0\n\ts_waitcnt vmcnt(0)"
                 : "=&v"(v) : "v"(p) : "memory");
    return v;
}
__device__ __forceinline__ void l2st(u32* p, u32 v) {
    asm volatile("global_store_dword %0, %1, off sc0" :: "v"(p), "v"(v) : "memory");
}
__device__ __forceinline__ unsigned short f2bf(float f) {
    u32 u = __float_as_uint(f);
    u += 0x7FFFu + ((u >> 16) & 1u);
    return (unsigned short)(u >> 16);
}
__device__ __forceinline__ bf16x8 cvt8(const float* p) {
    bf16x8 r;
#pragma unroll
    for (int i = 0; i < 8; ++i) r[i] = (__bf16)p[i];
    return r;
}

__global__ void __launch_bounds__(256, 1)
rnn_persistent(const float* __restrict__ x,
               const float* __restrict__ Wjx, const float* __restrict__ bjx,
               const float* __restrict__ Wjh, const float* __restrict__ bjh,
               const float* __restrict__ Wkx, const float* __restrict__ bkx,
               const float* __restrict__ Wkh, const float* __restrict__ bkh,
               float* __restrict__ out,   // [SEQ][B][H] outputs + [2][B][H] hidden
               u32* __restrict__ ring0,   // ws: [RING][B][H] stamped L0 h (LLC)
               u32* __restrict__ ring1,   // ws: [RING][B][H] stamped L1 h (fallback)
               u32* __restrict__ xch,     // ws: [8][4][16][512] exchange + tokens (XCD-L2)
               u32* __restrict__ ctrl,    // ws: barrier/fail/abort/BPF
               int allowFast)
{
    const int tid  = threadIdx.x;
    const int wave = tid >> 6;
    const int lane = tid & 63;
    const int wg   = blockIdx.x;

    const int cluster = wg & 7;      // heuristic XCD id (verified below)
    const int rank    = wg >> 3;     // 0..31 within cluster
    u32* xtok = xch + 262144;        // token lines, 64B apart

    // ---------------- startup: verify grouping, pick mode ----------------
    if (allowFast) {
        if (tid == 0) l2st(xtok + (((cluster << 5) + rank) << 4), 0xA5A5u);
        bool localOK = false;
        u32 it = 0;
        while (true) {
            u32 v = 0xA5A5u;
            if (lane < 32) v = l2ld(xtok + (((cluster << 5) + (lane & 31)) << 4));
            if (__all(v == 0xA5A5u)) { localOK = true; break; }
            if (++it > HSHAKE_IT) break;
            __builtin_amdgcn_s_sleep(4);
        }
        if (tid == 0 && !localOK) cstore(ctrl + C_FAIL, 1u);
    } else {
        if (tid == 0) cstore(ctrl + C_FAIL, 1u);
    }
    __syncthreads();
    if (tid == 0) {
        __hip_atomic_fetch_add(ctrl + C_BAR0, 1u, __ATOMIC_RELAXED, __HIP_MEMORY_SCOPE_AGENT);
        u32 it = 0;
        while (cload(ctrl + C_BAR0) < 256u) {
            if (++it > SPIN_INIT) { cstore(ctrl + C_FAIL, 1u); break; }
            __builtin_amdgcn_s_sleep(2);
        }
    }
    __syncthreads();
    const bool fast = (cload(ctrl + C_FAIL) == 0u);   // uniform across the grid

    int layer, mg, ng;
    if (fast) { layer = cluster >> 2; mg = cluster & 3; ng = rank; }
    else      { layer = wg >> 7;      mg = (wg >> 5) & 3; ng = wg & 31; }

    // ---------------- stationary weights -> bf16 VGPR frags ----------------
    const int ucol = ng * 16 + (lane & 15);
    const int koff = (wave & 1) * 256 + ((lane >> 4) << 3);
    const float* wjsrc = ((wave < 2) ? Wjx : Wjh) + (size_t)layer * Hn * Hn + (size_t)ucol * Hn + koff;
    const float* wksrc = ((wave < 2) ? Wkx : Wkh) + (size_t)layer * Hn * Hn + (size_t)ucol * Hn + koff;
    bf16x8 wj[8], wk[8];
#pragma unroll
    for (int kt = 0; kt < 8; ++kt) {
        wj[kt] = cvt8(wjsrc + kt * 32);
        wk[kt] = cvt8(wksrc + kt * 32);
    }

    const int ml = tid >> 4;
    const int nu = tid & 15;
    const int ue = ng * 16 + nu;
    const int be = mg * 16 + ml;
    const float bje = bjx[layer * Hn + ue] + bjh[layer * Hn + ue];
    const float bke = bkx[layer * Hn + ue] + bkh[layer * Hn + ue];

    __shared__ float part[4][2][16][16];
    __shared__ char  xT[16384];
    __shared__ char  hT[16384];

    const int m = mg * 16 + (lane & 15);

    auto compute_global = [&](const float* Abase) {
        f32x4 aj = {0.f, 0.f, 0.f, 0.f}, ak = {0.f, 0.f, 0.f, 0.f};
        const float* arow = Abase + (size_t)m * Hn + koff;
#pragma unroll
        for (int kt = 0; kt < 8; ++kt) {
            bf16x8 af = cvt8(arow + kt * 32);
            aj = __builtin_amdgcn_mfma_f32_16x16x32_bf16(af, wj[kt], aj, 0, 0, 0);
            ak = __builtin_amdgcn_mfma_f32_16x16x32_bf16(af, wk[kt], ak, 0, 0, 0);
        }
#pragma unroll
        for (int r = 0; r < 4; ++r) {
            part[wave][0][((lane >> 4) << 2) + r][lane & 15] = aj[r];
            part[wave][1][((lane >> 4) << 2) + r][lane & 15] = ak[r];
        }
    };
    auto compute_lds = [&](const char* tile) {
        f32x4 aj = {0.f, 0.f, 0.f, 0.f}, ak = {0.f, 0.f, 0.f, 0.f};
        const int r       = lane & 15;
        const int cb      = ((wave & 1) << 8) + ((lane >> 4) << 3);
        const int swz     = (r & 7) << 4;
        const int rowbase = r << 10;
#pragma unroll
        for (int kt = 0; kt < 8; ++kt) {
            const int c = cb + kt * 32;
            bf16x8 af = *(const bf16x8*)(tile + ((rowbase + (c << 1)) ^ swz));
            aj = __builtin_amdgcn_mfma_f32_16x16x32_bf16(af, wj[kt], aj, 0, 0, 0);
            ak = __builtin_amdgcn_mfma_f32_16x16x32_bf16(af, wk[kt], ak, 0, 0, 0);
        }
#pragma unroll
        for (int r2 = 0; r2 < 4; ++r2) {
            part[wave][0][((lane >> 4) << 2) + r2][lane & 15] = aj[r2];
            part[wave][1][((lane >> 4) << 2) + r2][lane & 15] = ak[r2];
        }
    };
    auto zero_store = [&]() {
#pragma unroll
        for (int r2 = 0; r2 < 4; ++r2) {
            part[wave][0][((lane >> 4) << 2) + r2][lane & 15] = 0.f;
            part[wave][1][((lane >> 4) << 2) + r2][lane & 15] = 0.f;
        }
    };
    auto stage_llc = [&](const u32* src, char* dstT, u32 want) {
        u32 v[32];
        u32 it = 0;
        while (true) {
            bool ok = true;
#pragma unroll
            for (int b = 0; b < 32; ++b) v[b] = cload(src + (b << 8) + tid);
#pragma unroll
            for (int b = 0; b < 32; ++b) ok &= ((v[b] & 0xFFFFu) == want);
            if (__all(ok)) break;
            if ((it & 255u) == 255u && cload(ctrl + C_ABORT)) break;
            if (++it > SPIN_MAIN) { cstore(ctrl + C_ABORT, 1u); break; }
            __builtin_amdgcn_s_sleep(1);
        }
#pragma unroll
        for (int b = 0; b < 32; ++b) {
            const int d = (b << 8) + tid, r = d >> 9;
            *(unsigned short*)(dstT + ((d << 1) ^ ((r & 7) << 4))) =
                (unsigned short)(v[b] >> 16);
        }
    };
    auto bpf_wait = [&](int want) {
        u32 it = 0;
        while (true) {
            int fv = (int)cload(ctrl + C_BPF + (mg << 5) + (lane & 31));
            if (__all(fv >= want)) break;
            if ((it & 255u) == 255u && cload(ctrl + C_ABORT)) break;
            if (++it > SPIN_MAIN) { cstore(ctrl + C_ABORT, 1u); break; }
            __builtin_amdgcn_s_sleep(1);
        }
    };
    // sc0 poll of a stamped 16x512 tile in the local XCD L2 -> swizzled bf16 hT
    auto stage_xch = [&](const u32* tile, u32 want) {
        const char* p0 = (const char*)tile + tid * 16;
        u32x4v v0, v1, v2, v3, v4, v5, v6, v7;
        u32 it = 0;
        while (true) {
            asm volatile(
                "global_load_dwordx4 %0, %8, off sc0\n\t"
                "global_load_dwordx4 %1, %9, off sc0\n\t"
                "global_load_dwordx4 %2, %10, off sc0\n\t"
                "global_load_dwordx4 %3, %11, off sc0\n\t"
                "global_load_dwordx4 %4, %12, off sc0\n\t"
                "global_load_dwordx4 %5, %13, off sc0\n\t"
                "global_load_dwordx4 %6, %14, off sc0\n\t"
                "global_load_dwordx4 %7, %15, off sc0\n\t"
                "s_waitcnt vmcnt(0)"
                : "=&v"(v0), "=&v"(v1), "=&v"(v2), "=&v"(v3),
                  "=&v"(v4), "=&v"(v5), "=&v"(v6), "=&v"(v7)
                : "v"(p0), "v"(p0 + 4096), "v"(p0 + 8192), "v"(p0 + 12288),
                  "v"(p0 + 16384), "v"(p0 + 20480), "v"(p0 + 24576), "v"(p0 + 28672)
                : "memory");
            bool ok = true;
#pragma unroll
            for (int i = 0; i < 4; ++i) {
                ok &= ((v0[i] & 0xFFFFu) == want); ok &= ((v1[i] & 0xFFFFu) == want);
                ok &= ((v2[i] & 0xFFFFu) == want); ok &= ((v3[i] & 0xFFFFu) == want);
                ok &= ((v4[i] & 0xFFFFu) == want); ok &= ((v5[i] & 0xFFFFu) == want);
                ok &= ((v6[i] & 0xFFFFu) == want); ok &= ((v7[i] & 0xFFFFu) == want);
            }
            if (__all(ok)) break;
            if ((it & 255u) == 255u && cload(ctrl + C_ABORT)) break;
            if (++it > SPIN_MAIN) { cstore(ctrl + C_ABORT, 1u); break; }
            __builtin_amdgcn_s_sleep(1);
        }
        const int cb2 = (tid << 2) & 511;
        const int rb  = tid >> 7;
#define CMT(bb, vv) { const int r = 2 * (bb) + rb;                              \
        u32 lo = ((vv)[0] >> 16) | ((vv)[1] & 0xFFFF0000u);                     \
        u32 hi = ((vv)[2] >> 16) | ((vv)[3] & 0xFFFF0000u);                     \
        const int ba = ((((r << 9) + cb2) << 1) ^ ((r & 7) << 4));              \
        *(u64*)(hT + ba) = (u64)lo | ((u64)hi << 32); }
        CMT(0, v0) CMT(1, v1) CMT(2, v2) CMT(3, v3)
        CMT(4, v4) CMT(5, v5) CMT(6, v6) CMT(7, v7)
#undef CMT
    };

    float hprev = 0.f;

    if (fast) {
        // ===================== XCD-LOCAL FAST PATH =====================
        u32* xchC = xch + (size_t)cluster * 4 * TILE;
        for (int t = 0; t < SEQn; ++t) {
            if (layer == 0 && wave < 2)
                compute_global(x + (size_t)t * BH);

            if (t > 0) stage_xch(xchC + (size_t)((t - 1) & 3) * TILE, (u32)t);
            if (layer == 1)
                stage_llc(ring0 + (size_t)(t & 7) * BH + mg * TILE, xT, (u32)(t + 1));
            __syncthreads();   // A
            if (layer == 1 && tid == 0)
                cstore(ctrl + C_BPF + (mg << 5) + ng, (u32)(t + 1));

            if (layer == 0) { if (wave >= 2) { if (t > 0) compute_lds(hT); else zero_store(); } }
            else { if (wave < 2) compute_lds(xT); else { if (t > 0) compute_lds(hT); else zero_store(); } }
            __syncthreads();   // B

            float sj = part[0][0][ml][nu] + part[1][0][ml][nu] +
                       part[2][0][ml][nu] + part[3][0][ml][nu] + bje;
            float sk = part[0][1][ml][nu] + part[1][1][ml][nu] +
                       part[2][1][ml][nu] + part[3][1][ml][nu] + bke;
            float jj = 1.f / (1.f + __expf(-sj));
            float kk = 1.f / (1.f + __expf(-sk));
            float hnew = jj * (1.f - hprev) + (1.f - kk) * hprev;
            hprev = hnew;

            const u32 word = ((u32)f2bf(hnew) << 16) | (u32)(t + 1);
            l2st(xchC + (size_t)(t & 3) * TILE + (ml << 9) + ue, word);   // local peers
            if (layer == 0) {
                if (t >= RING) bpf_wait(t - RING + 1);
                cstore(ring0 + (size_t)(t & 7) * BH + (be << 9) + ue, word);  // -> L1 (LLC)
            } else {
                out[(size_t)t * BH + (be << 9) + ue] = hnew;
            }
            if (t == SEQn - 1)
                out[(size_t)SEQn * BH + (size_t)layer * BH + (be << 9) + ue] = hnew;
            __syncthreads();   // C
        }
    } else {
        // ===================== LLC FALLBACK (round-9, bounded) =====================
        for (int t = 0; t < SEQn; ++t) {
            const u32* hsrc = (layer == 0 ? ring0 : ring1)
                              + (size_t)((t - 1) & (RING - 1)) * BH + mg * TILE;
            const u32* xsrc = ring0 + (size_t)(t & (RING - 1)) * BH + mg * TILE;

            if (layer == 0 && wave < 2)
                compute_global(x + (size_t)t * BH);

            if (layer == 0) {
                if (t >= RING) bpf_wait(t - RING + 1);
                if (t > 0) stage_llc(hsrc, hT, (u32)t);
            } else {
                if (t > 0) stage_llc(hsrc, hT, (u32)t);
                stage_llc(xsrc, xT, (u32)(t + 1));
            }
            __syncthreads();   // A
            if (layer == 1 && tid == 0)
                cstore(ctrl + C_BPF + (mg << 5) + ng, (u32)(t + 1));

            if (layer == 0) { if (wave >= 2) { if (t > 0) compute_lds(hT); else zero_store(); } }
            else { if (wave < 2) compute_lds(xT); else { if (t > 0) compute_lds(hT); else zero_store(); } }
            __syncthreads();   // B

            float sj = part[0][0][ml][nu] + part[1][0][ml][nu] +
                       part[2][0][ml][nu] + part[3][0][ml][nu] + bje;
            float sk = part[0][1][ml][nu] + part[1][1][ml][nu] +
                       part[2][1][ml][nu] + part[3][1][ml][nu] + bke;
            float jj = 1.f / (1.f + __expf(-sj));
            float kk = 1.f / (1.f + __expf(-sk));
            float hnew = jj * (1.f - hprev) + (1.f - kk) * hprev;
            hprev = hnew;

            const u32 word = ((u32)f2bf(hnew) << 16) | (u32)(t + 1);
            cstore((layer == 0 ? ring0 : ring1) + (size_t)(t & (RING - 1)) * BH + (be << 9) + ue, word);
            if (layer == 1)
                out[(size_t)t * BH + (be << 9) + ue] = hnew;
            if (t == SEQn - 1)
                out[(size_t)SEQn * BH + (size_t)layer * BH + (be << 9) + ue] = hnew;
            __syncthreads();   // C
        }
    }

    // erase tokens so stale ones can't false-pass the next graph replay
    if (allowFast && tid == 0)
        l2st(xtok + (((cluster << 5) + rank) << 4), 0xDEADu);
}

extern "C" void kernel_launch(void* const* d_in, const int* in_sizes, int n_in,
                              void* d_out, int out_size, void* d_ws, size_t ws_size,
                              hipStream_t stream) {
    (void)in_sizes; (void)n_in; (void)out_size;

    const float* x   = (const float*)d_in[0];
    const float* Wjx = (const float*)d_in[1];
    const float* bjx = (const float*)d_in[2];
    const float* Wjh = (const float*)d_in[3];
    const float* bjh = (const float*)d_in[4];
    const float* Wkx = (const float*)d_in[5];
    const float* bkx = (const float*)d_in[6];
    const float* Wkh = (const float*)d_in[7];
    const float* bkh = (const float*)d_in[8];
    float* out = (float*)d_out;

    char* ws = (char*)d_ws;
    u32* ring0 = (u32*)ws;                        // 1 MB   (LLC, stamped)
    u32* ring1 = (u32*)(ws + 1048576);            // 1 MB   (LLC, fallback only)
    u32* ctrl  = (u32*)(ws + 2097152);            // 4 KB   (LLC)
    u32* xch   = (u32*)(ws + 2101248);            // 1 MB exchange + 16 KB tokens (XCD-L2)
    const size_t need = 2101248u + 1048576u + 16384u;
    int allowFast = (ws_size >= need) ? 1 : 0;

    // zero only LLC-protocol state; xch/tokens live in XCD L2s (kernel-managed)
    hipMemsetAsync(ws, 0, 2101248, stream);

    void* args[] = { (void*)&x, (void*)&Wjx, (void*)&bjx, (void*)&Wjh, (void*)&bjh,
                     (void*)&Wkx, (void*)&bkx, (void*)&Wkh, (void*)&bkh,
                     (void*)&out, (void*)&ring0, (void*)&ring1, (void*)&xch, (void*)&ctrl,
                     (void*)&allowFast };
    hipError_t err = hipLaunchCooperativeKernel((void*)rnn_persistent,
                                                dim3(256), dim3(256), args, 0, stream);
    if (err != hipSuccess) {
        // silent-cooperative-failure class (rounds 6/11): plain launch instead.
        // 256 blocks x 1/CU on 256 CUs are co-resident; spins are bounded.
        hipLaunchKernelGGL(rnn_persistent, dim3(256), dim3(256), 0, stream,
                           x, Wjx, bjx, Wjh, bjh, Wkx, bkx, Wkh, bkh,
                           out, ring0, ring1, xch, ctrl, allowFast);
    }
}

// Round 13
// 2691.389 us; speedup vs baseline: 5.9857x; 5.9857x over previous
//
#include <hip/hip_runtime.h>
#include <hip/hip_bf16.h>

// FF_27650999451977: 2-layer gated RNN (MGU), SEQ=512, B=64, H=IN=512, FP32 I/O.
// Round-13: round-9 stamped-data LLC protocol (proven 2763us) + congestion fix:
//  - SENTINEL-FIRST polling: poll 1 stamped word per producer (32 lines/WG/iter,
//    16x less LLC poll traffic than the full 512-line sweep), full sweep only
//    after sentinels pass (then it exits in ~1 iteration).
//  - part[] double-buffered by t&1 -> barrier C removed (2 barriers/step).
//  - all spins iteration-bounded (visible failure, never a hang); cooperative
//    launch return checked with plain-launch fallback.

#define SEQn 512
#define Bn   64
#define Hn   512
#define RING 8
#define BH   32768      // Bn*Hn dwords
#define TILE 8192       // 16*512 dwords

#define SPIN_MAIN 65536u

typedef __bf16 bf16x8 __attribute__((ext_vector_type(8)));
typedef float  f32x4  __attribute__((ext_vector_type(4)));
typedef unsigned u32;
typedef unsigned long long u64;

__device__ __forceinline__ u32 cload(const u32* p) {
    return __hip_atomic_load(p, __ATOMIC_RELAXED, __HIP_MEMORY_SCOPE_AGENT);
}
__device__ __forceinline__ void cstore(u32* p, u32 v) {
    __hip_atomic_store(p, v, __ATOMIC_RELAXED, __HIP_MEMORY_SCOPE_AGENT);
}
__device__ __forceinline__ unsigned short f2bf(float f) {
    u32 u = __float_as_uint(f);
    u += 0x7FFFu + ((u >> 16) & 1u);   // round-to-nearest-even
    return (unsigned short)(u >> 16);
}
__device__ __forceinline__ bf16x8 cvt8(const float* p) {
    bf16x8 r;
#pragma unroll
    for (int i = 0; i < 8; ++i) r[i] = (__bf16)p[i];
    return r;
}

__global__ void __launch_bounds__(256, 1)
rnn_persistent(const float* __restrict__ x,
               const float* __restrict__ Wjx, const float* __restrict__ bjx,
               const float* __restrict__ Wjh, const float* __restrict__ bjh,
               const float* __restrict__ Wkx, const float* __restrict__ bkx,
               const float* __restrict__ Wkh, const float* __restrict__ bkh,
               float* __restrict__ out,   // [SEQ][B][H] outputs + [2][B][H] hidden
               u32* __restrict__ ring0,   // ws: [RING][B][H] stamped L0 h
               u32* __restrict__ ring1,   // ws: [RING][B][H] stamped L1 h
               u32* __restrict__ flags)   // ws: [4][32] L1 staging progress
{
    const int wg    = blockIdx.x;
    const int layer = wg >> 7;       // 0..1
    const int id    = wg & 127;
    const int mg    = id >> 5;       // 0..3  (16 batch rows each)
    const int ng    = id & 31;       // 0..31 (16 output units each)
    const int tid   = threadIdx.x;
    const int wave  = tid >> 6;      // 0..3  (waves 0,1 = x-side, 2,3 = h-side)
    const int lane  = tid & 63;

    // ---- stationary weights -> bf16 VGPR frags (B-operand: col = lane&15) ----
    const int ucol = ng * 16 + (lane & 15);
    const int koff = (wave & 1) * 256 + ((lane >> 4) << 3);
    const float* wjsrc = ((wave < 2) ? Wjx : Wjh) + (size_t)layer * Hn * Hn + (size_t)ucol * Hn + koff;
    const float* wksrc = ((wave < 2) ? Wkx : Wkh) + (size_t)layer * Hn * Hn + (size_t)ucol * Hn + koff;
    bf16x8 wj[8], wk[8];
#pragma unroll
    for (int kt = 0; kt < 8; ++kt) {
        wj[kt] = cvt8(wjsrc + kt * 32);
        wk[kt] = cvt8(wksrc + kt * 32);
    }

    // ---- epilogue constants: thread tid -> output (row ml, unit nu) ----
    const int ml = tid >> 4;
    const int nu = tid & 15;
    const int ue = ng * 16 + nu;
    const int be = mg * 16 + ml;
    const float bje = bjx[layer * Hn + ue] + bjh[layer * Hn + ue];
    const float bke = bkx[layer * Hn + ue] + bkh[layer * Hn + ue];

    __shared__ float part[2][4][2][16][16];   // 16 KB, double-buffered by t&1
    __shared__ char  xT[16384];
    __shared__ char  hT[16384];

    const int m = mg * 16 + (lane & 15);

    auto compute_global = [&](const float* Abase, int pb) {
        f32x4 aj = {0.f, 0.f, 0.f, 0.f}, ak = {0.f, 0.f, 0.f, 0.f};
        const float* arow = Abase + (size_t)m * Hn + koff;
#pragma unroll
        for (int kt = 0; kt < 8; ++kt) {
            bf16x8 af = cvt8(arow + kt * 32);
            aj = __builtin_amdgcn_mfma_f32_16x16x32_bf16(af, wj[kt], aj, 0, 0, 0);
            ak = __builtin_amdgcn_mfma_f32_16x16x32_bf16(af, wk[kt], ak, 0, 0, 0);
        }
#pragma unroll
        for (int r = 0; r < 4; ++r) {
            part[pb][wave][0][((lane >> 4) << 2) + r][lane & 15] = aj[r];
            part[pb][wave][1][((lane >> 4) << 2) + r][lane & 15] = ak[r];
        }
    };
    auto compute_lds = [&](const char* tile, int pb) {
        f32x4 aj = {0.f, 0.f, 0.f, 0.f}, ak = {0.f, 0.f, 0.f, 0.f};
        const int r       = lane & 15;
        const int cb      = ((wave & 1) << 8) + ((lane >> 4) << 3);
        const int swz     = (r & 7) << 4;
        const int rowbase = r << 10;
#pragma unroll
        for (int kt = 0; kt < 8; ++kt) {
            const int c = cb + kt * 32;
            bf16x8 af = *(const bf16x8*)(tile + ((rowbase + (c << 1)) ^ swz));
            aj = __builtin_amdgcn_mfma_f32_16x16x32_bf16(af, wj[kt], aj, 0, 0, 0);
            ak = __builtin_amdgcn_mfma_f32_16x16x32_bf16(af, wk[kt], ak, 0, 0, 0);
        }
#pragma unroll
        for (int r2 = 0; r2 < 4; ++r2) {
            part[pb][wave][0][((lane >> 4) << 2) + r2][lane & 15] = aj[r2];
            part[pb][wave][1][((lane >> 4) << 2) + r2][lane & 15] = ak[r2];
        }
    };
    auto zero_store = [&](int pb) {
#pragma unroll
        for (int r2 = 0; r2 < 4; ++r2) {
            part[pb][wave][0][((lane >> 4) << 2) + r2][lane & 15] = 0.f;
            part[pb][wave][1][((lane >> 4) << 2) + r2][lane & 15] = 0.f;
        }
    };
    // stamped-tile staging: sentinel-first (32 lines/iter), then full sweep.
    auto stage_llc = [&](const u32* src, char* dstT, u32 want, bool sent) {
        if (sent) {
            const int p = tid & 31;                       // producer sampled by this thread
            const u32* sp = src + (((p & 15) << 9) | (p << 4) | 15);
            u32 it = 0;
            while (true) {
                u32 s = cload(sp);
                if (__all((s & 0xFFFFu) == want)) break;
                if (++it > SPIN_MAIN) break;              // bounded: fail visibly
                __builtin_amdgcn_s_sleep(1);
            }
        }
        u32 v[32];
        u32 it = 0;
        while (true) {
            bool ok = true;
#pragma unroll
            for (int b = 0; b < 32; ++b) v[b] = cload(src + (b << 8) + tid);
#pragma unroll
            for (int b = 0; b < 32; ++b) ok &= ((v[b] & 0xFFFFu) == want);
            if (__all(ok)) break;
            if (++it > SPIN_MAIN) break;
            __builtin_amdgcn_s_sleep(1);
        }
#pragma unroll
        for (int b = 0; b < 32; ++b) {
            const int d = (b << 8) + tid, r = d >> 9;
            *(unsigned short*)(dstT + ((d << 1) ^ ((r & 7) << 4))) =
                (unsigned short)(v[b] >> 16);
        }
    };
    auto bpf_wait = [&](int want) {                      // 2 cache lines per iter
        u32 it = 0;
        while (true) {
            int fv = (int)cload(flags + (mg << 5) + (lane & 31));
            if (__all(fv >= want)) break;
            if (++it > SPIN_MAIN) break;
            __builtin_amdgcn_s_sleep(1);
        }
    };

    float hprev = 0.f;   // this thread's own h(be,ue) — exact fp32, in register

    for (int t = 0; t < SEQn; ++t) {
        const int pb    = t & 1;
        const int slot  = t & (RING - 1);
        const int pslot = (t - 1) & (RING - 1);
        const u32* hsrc = (layer == 0 ? ring0 : ring1)
                          + (size_t)pslot * BH + mg * TILE;
        const u32* xsrc = ring0 + (size_t)slot * BH + mg * TILE;

        // layer-0 x-side: static input, compute before the wait (fills spin time)
        if (layer == 0 && wave < 2)
            compute_global(x + (size_t)t * BH, pb);

        if (layer == 0) {
            if (t >= RING) bpf_wait(t - RING + 1);             // ring back-pressure
            if (t > 0) stage_llc(hsrc, hT, (u32)t, true);      // the real wait
        } else {
            stage_llc(hsrc, hT, (u32)t, false);                // own history: ready
            stage_llc(xsrc, xT, (u32)(t + 1), true);           // fresh L0 output
        }
        __syncthreads();   // A: tiles staged

        if (layer == 1 && tid == 0)
            cstore(flags + (mg << 5) + ng, (u32)(t + 1));

        if (layer == 0) { if (wave >= 2) { if (t > 0) compute_lds(hT, pb); else zero_store(pb); } }
        else            { if (wave < 2) compute_lds(xT, pb); else compute_lds(hT, pb); }
        __syncthreads();   // B: part[pb] complete

        // ---- epilogue ----
        float sj = part[pb][0][0][ml][nu] + part[pb][1][0][ml][nu] +
                   part[pb][2][0][ml][nu] + part[pb][3][0][ml][nu] + bje;
        float sk = part[pb][0][1][ml][nu] + part[pb][1][1][ml][nu] +
                   part[pb][2][1][ml][nu] + part[pb][3][1][ml][nu] + bke;
        float jj = 1.f / (1.f + __expf(-sj));
        float kk = 1.f / (1.f + __expf(-sk));
        float hnew = jj * (1.f - hprev) + (1.f - kk) * hprev;
        hprev = hnew;

        // self-publishing stamped store (write-through to LLC)
        u32 word = ((u32)f2bf(hnew) << 16) | (u32)(t + 1);
        cstore((layer == 0 ? ring0 : ring1) + (size_t)slot * BH + (size_t)be * Hn + ue, word);

        if (layer == 1)
            out[(size_t)t * BH + (size_t)be * Hn + ue] = hnew;
        if (t == SEQn - 1)
            out[(size_t)SEQn * BH + (size_t)layer * BH + (size_t)be * Hn + ue] = hnew;
        // no barrier C: part[] double-buffered; tile writes happen post-B next iter
    }
}

extern "C" void kernel_launch(void* const* d_in, const int* in_sizes, int n_in,
                              void* d_out, int out_size, void* d_ws, size_t ws_size,
                              hipStream_t stream) {
    (void)in_sizes; (void)n_in; (void)out_size; (void)ws_size;

    const float* x   = (const float*)d_in[0];
    const float* Wjx = (const float*)d_in[1];
    const float* bjx = (const float*)d_in[2];
    const float* Wjh = (const float*)d_in[3];
    const float* bjh = (const float*)d_in[4];
    const float* Wkx = (const float*)d_in[5];
    const float* bkx = (const float*)d_in[6];
    const float* Wkh = (const float*)d_in[7];
    const float* bkh = (const float*)d_in[8];
    float* out = (float*)d_out;

    char* ws = (char*)d_ws;
    u32* ring0 = (u32*)ws;                       // 1 MB (stamped)
    u32* ring1 = (u32*)(ws + 1048576);           // 1 MB (stamped)
    u32* flags = (u32*)(ws + 2097152);           // 512 B (pad to 4 KB)

    hipMemsetAsync(ws, 0, 2097152 + 4096, stream);

    void* args[] = { (void*)&x, (void*)&Wjx, (void*)&bjx, (void*)&Wjh, (void*)&bjh,
                     (void*)&Wkx, (void*)&bkx, (void*)&Wkh, (void*)&bkh,
                     (void*)&out, (void*)&ring0, (void*)&ring1, (void*)&flags };
    hipError_t err = hipLaunchCooperativeKernel((void*)rnn_persistent, dim3(256),
                                                dim3(256), args, 0, stream);
    if (err != hipSuccess) {
        // 256 blocks at 1 block/CU on 256 CUs are co-resident; spins are bounded.
        hipLaunchKernelGGL(rnn_persistent, dim3(256), dim3(256), 0, stream,
                           x, Wjx, bjx, Wjh, bjh, Wkx, bkx, Wkh, bkh,
                           out, ring0, ring1, flags);
    }
}

// Round 14
// 2662.180 us; speedup vs baseline: 6.0514x; 1.0110x over previous
//
#include <hip/hip_runtime.h>
#include <hip/hip_bf16.h>

// FF_27650999451977: 2-layer gated RNN (MGU), SEQ=512, B=64, H=IN=512, FP32 I/O.
// Round-14: minimum-RT stamped-data protocol.
//  - single-phase sweep-poll (detect+transfer share one LLC RT; sentinel removed
//    -- r13 showed poll traffic is irrelevant and the sentinel serialized an RT)
//  - L1's own-history and x sweeps overlapped in one poll loop (2 serial RTs -> 1)
//  - L0 back-pressure folded into its sweep poll (33rd load; bwant<=0 autopasses)
//  - RING=16 so L1 lag never throttles L0
//  - part[] double-buffered (2 barriers/step), bounded spins, coop-launch check.

#define SEQn 512
#define Bn   64
#define Hn   512
#define RING 16
#define BH   32768      // Bn*Hn dwords
#define TILE 8192       // 16*512 dwords

#define SPIN_MAIN 262144u

typedef __bf16 bf16x8 __attribute__((ext_vector_type(8)));
typedef float  f32x4  __attribute__((ext_vector_type(4)));
typedef unsigned u32;

__device__ __forceinline__ u32 cload(const u32* p) {
    return __hip_atomic_load(p, __ATOMIC_RELAXED, __HIP_MEMORY_SCOPE_AGENT);
}
__device__ __forceinline__ void cstore(u32* p, u32 v) {
    __hip_atomic_store(p, v, __ATOMIC_RELAXED, __HIP_MEMORY_SCOPE_AGENT);
}
__device__ __forceinline__ unsigned short f2bf(float f) {
    u32 u = __float_as_uint(f);
    u += 0x7FFFu + ((u >> 16) & 1u);   // round-to-nearest-even
    return (unsigned short)(u >> 16);
}
__device__ __forceinline__ bf16x8 cvt8(const float* p) {
    bf16x8 r;
#pragma unroll
    for (int i = 0; i < 8; ++i) r[i] = (__bf16)p[i];
    return r;
}

__global__ void __launch_bounds__(256, 1)
rnn_persistent(const float* __restrict__ x,
               const float* __restrict__ Wjx, const float* __restrict__ bjx,
               const float* __restrict__ Wjh, const float* __restrict__ bjh,
               const float* __restrict__ Wkx, const float* __restrict__ bkx,
               const float* __restrict__ Wkh, const float* __restrict__ bkh,
               float* __restrict__ out,   // [SEQ][B][H] outputs + [2][B][H] hidden
               u32* __restrict__ ring0,   // ws: [RING][B][H] stamped L0 h
               u32* __restrict__ ring1,   // ws: [RING][B][H] stamped L1 h
               u32* __restrict__ flags)   // ws: [4][32] L1 x-consumption progress
{
    const int wg    = blockIdx.x;
    const int layer = wg >> 7;       // 0..1
    const int id    = wg & 127;
    const int mg    = id >> 5;       // 0..3  (16 batch rows each)
    const int ng    = id & 31;       // 0..31 (16 output units each)
    const int tid   = threadIdx.x;
    const int wave  = tid >> 6;      // 0..3  (waves 0,1 = x-side, 2,3 = h-side)
    const int lane  = tid & 63;

    // ---- stationary weights -> bf16 VGPR frags (B-operand: col = lane&15) ----
    const int ucol = ng * 16 + (lane & 15);
    const int koff = (wave & 1) * 256 + ((lane >> 4) << 3);
    const float* wjsrc = ((wave < 2) ? Wjx : Wjh) + (size_t)layer * Hn * Hn + (size_t)ucol * Hn + koff;
    const float* wksrc = ((wave < 2) ? Wkx : Wkh) + (size_t)layer * Hn * Hn + (size_t)ucol * Hn + koff;
    bf16x8 wj[8], wk[8];
#pragma unroll
    for (int kt = 0; kt < 8; ++kt) {
        wj[kt] = cvt8(wjsrc + kt * 32);
        wk[kt] = cvt8(wksrc + kt * 32);
    }

    // ---- epilogue constants: thread tid -> output (row ml, unit nu) ----
    const int ml = tid >> 4;
    const int nu = tid & 15;
    const int ue = ng * 16 + nu;
    const int be = mg * 16 + ml;
    const float bje = bjx[layer * Hn + ue] + bjh[layer * Hn + ue];
    const float bke = bkx[layer * Hn + ue] + bkh[layer * Hn + ue];

    __shared__ float part[2][4][2][16][16];   // 16 KB, double-buffered by t&1
    __shared__ char  xT[16384];
    __shared__ char  hT[16384];

    const int m = mg * 16 + (lane & 15);

    auto compute_global = [&](const float* Abase, int pb) {
        f32x4 aj = {0.f, 0.f, 0.f, 0.f}, ak = {0.f, 0.f, 0.f, 0.f};
        const float* arow = Abase + (size_t)m * Hn + koff;
#pragma unroll
        for (int kt = 0; kt < 8; ++kt) {
            bf16x8 af = cvt8(arow + kt * 32);
            aj = __builtin_amdgcn_mfma_f32_16x16x32_bf16(af, wj[kt], aj, 0, 0, 0);
            ak = __builtin_amdgcn_mfma_f32_16x16x32_bf16(af, wk[kt], ak, 0, 0, 0);
        }
#pragma unroll
        for (int r = 0; r < 4; ++r) {
            part[pb][wave][0][((lane >> 4) << 2) + r][lane & 15] = aj[r];
            part[pb][wave][1][((lane >> 4) << 2) + r][lane & 15] = ak[r];
        }
    };
    auto compute_lds = [&](const char* tile, int pb) {
        f32x4 aj = {0.f, 0.f, 0.f, 0.f}, ak = {0.f, 0.f, 0.f, 0.f};
        const int r       = lane & 15;
        const int cb      = ((wave & 1) << 8) + ((lane >> 4) << 3);
        const int swz     = (r & 7) << 4;
        const int rowbase = r << 10;
#pragma unroll
        for (int kt = 0; kt < 8; ++kt) {
            const int c = cb + kt * 32;
            bf16x8 af = *(const bf16x8*)(tile + ((rowbase + (c << 1)) ^ swz));
            aj = __builtin_amdgcn_mfma_f32_16x16x32_bf16(af, wj[kt], aj, 0, 0, 0);
            ak = __builtin_amdgcn_mfma_f32_16x16x32_bf16(af, wk[kt], ak, 0, 0, 0);
        }
#pragma unroll
        for (int r2 = 0; r2 < 4; ++r2) {
            part[pb][wave][0][((lane >> 4) << 2) + r2][lane & 15] = aj[r2];
            part[pb][wave][1][((lane >> 4) << 2) + r2][lane & 15] = ak[r2];
        }
    };
    auto zero_store = [&](int pb) {
#pragma unroll
        for (int r2 = 0; r2 < 4; ++r2) {
            part[pb][wave][0][((lane >> 4) << 2) + r2][lane & 15] = 0.f;
            part[pb][wave][1][((lane >> 4) << 2) + r2][lane & 15] = 0.f;
        }
    };

    // L0: single-phase sweep-poll with back-pressure folded in (33rd load).
    auto stage_l0 = [&](const u32* src, u32 want, int bwant) {
        u32 v[32];
        const u32* fp = flags + (mg << 5) + (lane & 31);
        u32 it = 0;
        while (true) {
            bool ok = true;
#pragma unroll
            for (int b = 0; b < 32; ++b) v[b] = cload(src + (b << 8) + tid);
            int fv = (int)cload(fp);
#pragma unroll
            for (int b = 0; b < 32; ++b) ok &= ((v[b] & 0xFFFFu) == want);
            ok &= (fv >= bwant);
            if (__all(ok)) break;
            if (++it > SPIN_MAIN) break;      // bounded: fail visibly, never hang
            __builtin_amdgcn_s_sleep(1);
        }
#pragma unroll
        for (int b = 0; b < 32; ++b) {
            const int d = (b << 8) + tid, r = d >> 9;
            *(unsigned short*)(hT + ((d << 1) ^ ((r & 7) << 4))) =
                (unsigned short)(v[b] >> 16);
        }
    };
    // L1: overlapped dual sweep-poll (own-history h + fresh x in one loop).
    auto stage_l1 = [&](const u32* hsrc, const u32* xsrc, u32 hwant, u32 xwant) {
        u32 vh[32], vx[32];
        bool hok = false, xok = false;
        u32 it = 0;
        while (true) {
            if (!hok) {
#pragma unroll
                for (int b = 0; b < 32; ++b) vh[b] = cload(hsrc + (b << 8) + tid);
            }
            if (!xok) {
#pragma unroll
                for (int b = 0; b < 32; ++b) vx[b] = cload(xsrc + (b << 8) + tid);
            }
            bool h2 = true, x2 = true;
#pragma unroll
            for (int b = 0; b < 32; ++b) h2 &= ((vh[b] & 0xFFFFu) == hwant);
#pragma unroll
            for (int b = 0; b < 32; ++b) x2 &= ((vx[b] & 0xFFFFu) == xwant);
            hok = hok || __all(h2);
            xok = xok || __all(x2);
            if (hok && xok) break;
            if (++it > SPIN_MAIN) break;
            __builtin_amdgcn_s_sleep(1);
        }
#pragma unroll
        for (int b = 0; b < 32; ++b) {
            const int d = (b << 8) + tid, r = d >> 9;
            *(unsigned short*)(hT + ((d << 1) ^ ((r & 7) << 4))) =
                (unsigned short)(vh[b] >> 16);
        }
#pragma unroll
        for (int b = 0; b < 32; ++b) {
            const int d = (b << 8) + tid, r = d >> 9;
            *(unsigned short*)(xT + ((d << 1) ^ ((r & 7) << 4))) =
                (unsigned short)(vx[b] >> 16);
        }
    };

    float hprev = 0.f;   // this thread's own h(be,ue) — exact fp32, in register

    for (int t = 0; t < SEQn; ++t) {
        const int pb    = t & 1;
        const int slot  = t & (RING - 1);
        const int pslot = (t - 1) & (RING - 1);
        const u32* hsrc = (layer == 0 ? ring0 : ring1)
                          + (size_t)pslot * BH + mg * TILE;
        const u32* xsrc = ring0 + (size_t)slot * BH + mg * TILE;

        // layer-0 x-side: static input; runs between the previous store and the
        // poll, overlapping the store-visibility window.
        if (layer == 0 && wave < 2)
            compute_global(x + (size_t)t * BH, pb);

        if (layer == 0) {
            if (t > 0) stage_l0(hsrc, (u32)t, t - RING + 1);
            // t==0: no wait; h-side waves will zero_store
        } else {
            stage_l1(hsrc, xsrc, (u32)t, (u32)(t + 1));
        }
        __syncthreads();   // A: tiles staged

        if (layer == 1 && tid == 0)
            cstore(flags + (mg << 5) + ng, (u32)(t + 1));

        if (layer == 0) { if (wave >= 2) { if (t > 0) compute_lds(hT, pb); else zero_store(pb); } }
        else            { if (wave < 2) compute_lds(xT, pb); else compute_lds(hT, pb); }
        __syncthreads();   // B: part[pb] complete

        // ---- epilogue ----
        float sj = part[pb][0][0][ml][nu] + part[pb][1][0][ml][nu] +
                   part[pb][2][0][ml][nu] + part[pb][3][0][ml][nu] + bje;
        float sk = part[pb][0][1][ml][nu] + part[pb][1][1][ml][nu] +
                   part[pb][2][1][ml][nu] + part[pb][3][1][ml][nu] + bke;
        float jj = 1.f / (1.f + __expf(-sj));
        float kk = 1.f / (1.f + __expf(-sk));
        float hnew = jj * (1.f - hprev) + (1.f - kk) * hprev;
        hprev = hnew;

        // self-publishing stamped store (write-through to LLC)
        u32 word = ((u32)f2bf(hnew) << 16) | (u32)(t + 1);
        cstore((layer == 0 ? ring0 : ring1) + (size_t)slot * BH + (size_t)be * Hn + ue, word);

        if (layer == 1)
            out[(size_t)t * BH + (size_t)be * Hn + ue] = hnew;
        if (t == SEQn - 1)
            out[(size_t)SEQn * BH + (size_t)layer * BH + (size_t)be * Hn + ue] = hnew;
        // no barrier C: part[] double-buffered; tile writes happen post-B next iter
    }
}

extern "C" void kernel_launch(void* const* d_in, const int* in_sizes, int n_in,
                              void* d_out, int out_size, void* d_ws, size_t ws_size,
                              hipStream_t stream) {
    (void)in_sizes; (void)n_in; (void)out_size; (void)ws_size;

    const float* x   = (const float*)d_in[0];
    const float* Wjx = (const float*)d_in[1];
    const float* bjx = (const float*)d_in[2];
    const float* Wjh = (const float*)d_in[3];
    const float* bjh = (const float*)d_in[4];
    const float* Wkx = (const float*)d_in[5];
    const float* bkx = (const float*)d_in[6];
    const float* Wkh = (const float*)d_in[7];
    const float* bkh = (const float*)d_in[8];
    float* out = (float*)d_out;

    char* ws = (char*)d_ws;
    u32* ring0 = (u32*)ws;                       // RING*128KB = 2 MB (stamped)
    u32* ring1 = (u32*)(ws + 2097152);           // 2 MB (stamped)
    u32* flags = (u32*)(ws + 4194304);           // 512 B (pad to 4 KB)

    hipMemsetAsync(ws, 0, 4194304 + 4096, stream);

    void* args[] = { (void*)&x, (void*)&Wjx, (void*)&bjx, (void*)&Wjh, (void*)&bjh,
                     (void*)&Wkx, (void*)&bkx, (void*)&Wkh, (void*)&bkh,
                     (void*)&out, (void*)&ring0, (void*)&ring1, (void*)&flags };
    hipError_t err = hipLaunchCooperativeKernel((void*)rnn_persistent, dim3(256),
                                                dim3(256), args, 0, stream);
    if (err != hipSuccess) {
        // 256 blocks at 1 block/CU on 256 CUs are co-resident; spins are bounded.
        hipLaunchKernelGGL(rnn_persistent, dim3(256), dim3(256), 0, stream,
                           x, Wjx, bjx, Wjh, bjh, Wkx, bkx, Wkh, bkh,
                           out, ring0, ring1, flags);
    }
}